// Round 2
// baseline (286.828 us; speedup 1.0000x reference)
//
#include <hip/hip_runtime.h>
#include <math.h>

// Sizes (fixed for this problem)
#define B    256
#define T    512
#define CTX  512
#define MEL  160
#define PRE  128
#define ATT  256
#define RNN  768
#define G3   2304   // 3*RNN

// ---------------------------------------------------------------------------
// Fused front: PreNet -> attention GRUCell -> q projection
// grid: 64 blocks (4 batches each), 256 threads
// writes: h_att_out (d_out slice), x_dec[:, 0:256], q (B,512)
// ---------------------------------------------------------------------------
__global__ __launch_bounds__(256) void front_kernel(
        const float* __restrict__ x,
        const float* __restrict__ pre_w1, const float* __restrict__ pre_b1,
        const float* __restrict__ pre_w2, const float* __restrict__ pre_b2,
        const float* __restrict__ h_att,
        const float* __restrict__ wi, const float* __restrict__ wh,
        const float* __restrict__ bi, const float* __restrict__ bh,
        const float* __restrict__ qw, const float* __restrict__ qb,
        float* __restrict__ h_att_out, float* __restrict__ x_dec,
        float* __restrict__ q) {
    __shared__ float xf[4][MEL];
    __shared__ float h1[4][PRE];
    __shared__ float hp[4][PRE];
    __shared__ float ha[4][ATT];
    __shared__ float ha2[4][ATT];
    const int tid = threadIdx.x;
    const int b0 = blockIdx.x * 4;

    for (int i = tid; i < 4 * MEL; i += 256) xf[i / MEL][i % MEL] = x[b0 * MEL + i];
    for (int i = tid; i < 4 * ATT; i += 256) ha[i >> 8][i & 255] = h_att[b0 * ATT + i];
    __syncthreads();

    // PreNet layer 1: 4*128 outputs, 2 per thread
    #pragma unroll
    for (int it = 0; it < 2; ++it) {
        const int oid = tid + it * 256;
        const int bl = oid >> 7, j = oid & 127;
        float a = pre_b1[j];
        const float* wr = pre_w1 + (size_t)j * MEL;
        #pragma unroll 4
        for (int k = 0; k < MEL; ++k) a += xf[bl][k] * wr[k];
        h1[bl][j] = fmaxf(a, 0.f);
    }
    __syncthreads();
    // PreNet layer 2
    #pragma unroll
    for (int it = 0; it < 2; ++it) {
        const int oid = tid + it * 256;
        const int bl = oid >> 7, j = oid & 127;
        float a = pre_b2[j];
        const float* wr = pre_w2 + (size_t)j * PRE;
        #pragma unroll 4
        for (int k = 0; k < PRE; ++k) a += h1[bl][k] * wr[k];
        hp[bl][j] = fmaxf(a, 0.f);
    }
    __syncthreads();

    // attention GRU: thread = output feature j, 4 batches in registers
    {
        const int j = tid;
        float gr[4], gz[4], gn[4], hr[4], hz[4], hn[4];
        const float bir = bi[j], biz = bi[ATT + j], bin = bi[2 * ATT + j];
        const float bhr = bh[j], bhz = bh[ATT + j], bhn = bh[2 * ATT + j];
        #pragma unroll
        for (int qq = 0; qq < 4; ++qq) { gr[qq] = bir; gz[qq] = biz; gn[qq] = bin; hr[qq] = bhr; hz[qq] = bhz; hn[qq] = bhn; }
        const float* wir = wi + (size_t)j * PRE;
        const float* wiz = wi + (size_t)(ATT + j) * PRE;
        const float* win = wi + (size_t)(2 * ATT + j) * PRE;
        for (int k = 0; k < PRE; ++k) {
            const float a = wir[k], c = wiz[k], d = win[k];
            #pragma unroll
            for (int qq = 0; qq < 4; ++qq) { const float h_ = hp[qq][k]; gr[qq] += a * h_; gz[qq] += c * h_; gn[qq] += d * h_; }
        }
        const float* whr = wh + (size_t)j * ATT;
        const float* whz = wh + (size_t)(ATT + j) * ATT;
        const float* whn = wh + (size_t)(2 * ATT + j) * ATT;
        for (int k = 0; k < ATT; ++k) {
            const float a = whr[k], c = whz[k], d = whn[k];
            #pragma unroll
            for (int qq = 0; qq < 4; ++qq) { const float h_ = ha[qq][k]; hr[qq] += a * h_; hz[qq] += c * h_; hn[qq] += d * h_; }
        }
        #pragma unroll
        for (int qq = 0; qq < 4; ++qq) {
            const float r = 1.f / (1.f + expf(-(gr[qq] + hr[qq])));
            const float z = 1.f / (1.f + expf(-(gz[qq] + hz[qq])));
            const float n = tanhf(gn[qq] + r * hn[qq]);
            const float hnew = (1.f - z) * n + z * ha[qq][j];
            ha2[qq][j] = hnew;
            h_att_out[(size_t)(b0 + qq) * ATT + j] = hnew;
            x_dec[(size_t)(b0 + qq) * RNN + j] = hnew;
        }
    }
    __syncthreads();

    // q projection: 4*512 outputs, 8 per thread
    #pragma unroll
    for (int it = 0; it < 8; ++it) {
        const int oid = tid + it * 256;
        const int bl = oid >> 9, c = oid & 511;
        float a = qb[c];
        const float* wr = qw + (size_t)c * ATT;
        #pragma unroll 4
        for (int k = 0; k < ATT; ++k) a += ha2[bl][k] * wr[k];
        q[(size_t)(b0 + bl) * CTX + c] = a;
    }
}

// ---------------------------------------------------------------------------
// Fused memory pass: one read of memory (B,T,CTX) producing
//   e[b,t]  = dot(memory[b,t,:], q[b,:]) / sqrt(CTX)
//   ctx_partial[slice][b][c] = sum_{t in slice} w[b,t] * memory[b,t,c]
// grid: dim3(8, B), 256 threads (4 waves x 16 t-rows each)
// ---------------------------------------------------------------------------
__global__ void mempass_kernel(const float* __restrict__ mem, const float* __restrict__ w,
                               const float* __restrict__ q, float* __restrict__ e,
                               float* __restrict__ ctx_part) {
    const int b = blockIdx.y, slice = blockIdx.x;
    const int tid = threadIdx.x;
    const int wave = tid >> 6, lane = tid & 63;
    __shared__ float qs[CTX];
    __shared__ float ctx_s[4][CTX];
    for (int i = tid; i < CTX; i += 256) qs[i] = q[(size_t)b * CTX + i];
    __syncthreads();

    const int c0 = lane * 4;
    const int c1 = 256 + lane * 4;
    const float q0 = qs[c0], q1 = qs[c0 + 1], q2 = qs[c0 + 2], q3 = qs[c0 + 3];
    const float q4 = qs[c1], q5 = qs[c1 + 1], q6 = qs[c1 + 2], q7 = qs[c1 + 3];

    const float* mb = mem + (size_t)b * T * CTX;
    float acc[8] = {0.f, 0.f, 0.f, 0.f, 0.f, 0.f, 0.f, 0.f};
    const float invs = 0.04419417382415922f;  // 1/sqrt(512)
    const int t0 = slice * 64 + wave * 16;

    for (int i = 0; i < 16; ++i) {
        const int t = t0 + i;
        const float* row = mb + (size_t)t * CTX;
        const float4 m0 = *(const float4*)(row + c0);
        const float4 m1 = *(const float4*)(row + c1);
        const float wt = w[(size_t)b * T + t];
        float ep = m0.x * q0 + m0.y * q1 + m0.z * q2 + m0.w * q3
                 + m1.x * q4 + m1.y * q5 + m1.z * q6 + m1.w * q7;
        #pragma unroll
        for (int off = 32; off; off >>= 1) ep += __shfl_xor(ep, off);
        if (lane == 0) e[(size_t)b * T + t] = ep * invs;
        acc[0] += wt * m0.x; acc[1] += wt * m0.y; acc[2] += wt * m0.z; acc[3] += wt * m0.w;
        acc[4] += wt * m1.x; acc[5] += wt * m1.y; acc[6] += wt * m1.z; acc[7] += wt * m1.w;
    }
    ctx_s[wave][c0] = acc[0]; ctx_s[wave][c0 + 1] = acc[1]; ctx_s[wave][c0 + 2] = acc[2]; ctx_s[wave][c0 + 3] = acc[3];
    ctx_s[wave][c1] = acc[4]; ctx_s[wave][c1 + 1] = acc[5]; ctx_s[wave][c1 + 2] = acc[6]; ctx_s[wave][c1 + 3] = acc[7];
    __syncthreads();
    for (int c = tid; c < CTX; c += 256) {
        const float s = ctx_s[0][c] + ctx_s[1][c] + ctx_s[2][c] + ctx_s[3][c];
        ctx_part[((size_t)slice * B + b) * CTX + c] = s;
    }
}

// ---------------------------------------------------------------------------
// Fused mid: blocks 0..511 reduce ctx partials -> x_dec[:, 256:768]
//            blocks 512..767 softmax * Markov prior -> w_new
// ---------------------------------------------------------------------------
__global__ void mid_kernel(const float* __restrict__ part, float* __restrict__ x_dec,
                           const float* __restrict__ e, const float* __restrict__ w,
                           float* __restrict__ w_new) {
    const int tid = threadIdx.x;
    if (blockIdx.x < 512) {
        const int idx = blockIdx.x * 256 + tid;  // 131072 total
        const int b = idx >> 9, c = idx & 511;
        float s = 0.f;
        #pragma unroll
        for (int sl = 0; sl < 8; ++sl) s += part[((size_t)sl * B + b) * CTX + c];
        x_dec[(size_t)b * RNN + ATT + c] = s;
        return;
    }
    const int b = blockIdx.x - 512;
    const int lane = tid & 63, wv = tid >> 6;
    __shared__ float red[4];
    const float* eb = e + (size_t)b * T;
    const float* wb = w + (size_t)b * T;
    const float e0 = eb[tid], e1 = eb[tid + 256];

    float m = fmaxf(e0, e1);
    #pragma unroll
    for (int o = 32; o; o >>= 1) m = fmaxf(m, __shfl_xor(m, o));
    if (lane == 0) red[wv] = m;
    __syncthreads();
    m = fmaxf(fmaxf(red[0], red[1]), fmaxf(red[2], red[3]));
    __syncthreads();

    const float x0 = expf(e0 - m), x1 = expf(e1 - m);
    float s = x0 + x1;
    #pragma unroll
    for (int o = 32; o; o >>= 1) s += __shfl_xor(s, o);
    if (lane == 0) red[wv] = s;
    __syncthreads();
    s = red[0] + red[1] + red[2] + red[3];
    __syncthreads();

    const float p0 = 0.5f * (wb[tid] + (tid > 0 ? wb[tid - 1] : 0.f));
    const float p1 = 0.5f * (wb[tid + 256] + wb[tid + 255]);
    const float m0 = (x0 / s) * p0;
    const float m1 = (x1 / s) * p1;
    float s2 = m0 + m1;
    #pragma unroll
    for (int o = 32; o; o >>= 1) s2 += __shfl_xor(s2, o);
    if (lane == 0) red[wv] = s2;
    __syncthreads();
    s2 = red[0] + red[1] + red[2] + red[3];
    const float inv = 1.f / (s2 + 1e-8f);
    w_new[(size_t)b * T + tid] = m0 * inv;
    w_new[(size_t)b * T + tid + 256] = m1 * inv;
}

// ---------------------------------------------------------------------------
// Split-K fp32 GEMM: C[s][256,2304] += A[256, ks:ks+192] @ W[2304, ks:ks+192]^T
// blockIdx.z in [0,8): mat = z>>2 (0: gi = A_gi@W_gi^T, 1: gh), s = z&3
// 128x128 tile, BK=16, 256 threads, 8x8 micro-tile. Partials to ws.
// ---------------------------------------------------------------------------
#define GBM 128
#define GBN 128
#define GBK 16
#define KSPLIT 4
#define KCHUNK (RNN / KSPLIT)   // 192
__global__ __launch_bounds__(256) void gemm_splitk_kernel(
        const float* __restrict__ Agi, const float* __restrict__ Agh,
        const float* __restrict__ Wgi, const float* __restrict__ Wgh,
        float* __restrict__ parts) {
    const int z = blockIdx.z;
    const int mat = z >> 2, s = z & 3;
    const float* __restrict__ A = mat ? Agh : Agi;
    const float* __restrict__ W = mat ? Wgh : Wgi;
    float* __restrict__ P = parts + (size_t)z * ((size_t)B * G3);

    const int m0 = blockIdx.y * GBM, n0 = blockIdx.x * GBN;
    __shared__ float As[GBK][GBM + 4];
    __shared__ float Ws[GBK][GBN + 4];
    const int tid = threadIdx.x;
    const int tx = tid & 15, ty = tid >> 4;
    const int lrow = tid >> 1, lc = (tid & 1) * 8;
    const int kbase = s * KCHUNK;

    float acc[8][8] = {};
    for (int kc = 0; kc < KCHUNK / GBK; ++kc) {
        const int k0 = kbase + kc * GBK;
        {
            const float* ap = A + (size_t)(m0 + lrow) * RNN + k0 + lc;
            const float4 v0 = *(const float4*)ap;
            const float4 v1 = *(const float4*)(ap + 4);
            As[lc + 0][lrow] = v0.x; As[lc + 1][lrow] = v0.y; As[lc + 2][lrow] = v0.z; As[lc + 3][lrow] = v0.w;
            As[lc + 4][lrow] = v1.x; As[lc + 5][lrow] = v1.y; As[lc + 6][lrow] = v1.z; As[lc + 7][lrow] = v1.w;
            const float* wp = W + (size_t)(n0 + lrow) * RNN + k0 + lc;
            const float4 u0 = *(const float4*)wp;
            const float4 u1 = *(const float4*)(wp + 4);
            Ws[lc + 0][lrow] = u0.x; Ws[lc + 1][lrow] = u0.y; Ws[lc + 2][lrow] = u0.z; Ws[lc + 3][lrow] = u0.w;
            Ws[lc + 4][lrow] = u1.x; Ws[lc + 5][lrow] = u1.y; Ws[lc + 6][lrow] = u1.z; Ws[lc + 7][lrow] = u1.w;
        }
        __syncthreads();
        #pragma unroll
        for (int kk = 0; kk < GBK; ++kk) {
            const float4 a0 = *(const float4*)&As[kk][ty * 8];
            const float4 a1 = *(const float4*)&As[kk][ty * 8 + 4];
            const float4 w0 = *(const float4*)&Ws[kk][tx * 8];
            const float4 w1 = *(const float4*)&Ws[kk][tx * 8 + 4];
            const float av[8] = {a0.x, a0.y, a0.z, a0.w, a1.x, a1.y, a1.z, a1.w};
            const float wv[8] = {w0.x, w0.y, w0.z, w0.w, w1.x, w1.y, w1.z, w1.w};
            #pragma unroll
            for (int i = 0; i < 8; ++i)
                #pragma unroll
                for (int j = 0; j < 8; ++j) acc[i][j] += av[i] * wv[j];
        }
        __syncthreads();
    }
    #pragma unroll
    for (int i = 0; i < 8; ++i) {
        const int row = m0 + ty * 8 + i;
        float* dst = P + (size_t)row * G3 + n0 + tx * 8;
        *(float4*)dst       = make_float4(acc[i][0], acc[i][1], acc[i][2], acc[i][3]);
        *(float4*)(dst + 4) = make_float4(acc[i][4], acc[i][5], acc[i][6], acc[i][7]);
    }
}

// ---------------------------------------------------------------------------
// Split-K reduce + bias + GRU epilogue + residual
// grid: 768 blocks, 256 threads (one (b,j) each)
// ---------------------------------------------------------------------------
__global__ void gru_reduce_kernel(const float* __restrict__ parts,
                                  const float* __restrict__ x_in, const float* __restrict__ h_prev,
                                  const float* __restrict__ bi, const float* __restrict__ bh,
                                  float* __restrict__ out0, float* __restrict__ out1) {
    const int idx = blockIdx.x * 256 + threadIdx.x;  // 196608 total
    const int b = idx / RNN, j = idx % RNN;
    const size_t base = (size_t)b * G3 + j;
    float ir = bi[j], iz = bi[RNN + j], in_ = bi[2 * RNN + j];
    float hr = bh[j], hz = bh[RNN + j], hn = bh[2 * RNN + j];
    #pragma unroll
    for (int s = 0; s < 4; ++s) {
        const float* p  = parts + (size_t)s * ((size_t)B * G3) + base;
        const float* ph = parts + (size_t)(4 + s) * ((size_t)B * G3) + base;
        ir += p[0];  iz += p[RNN];  in_ += p[2 * RNN];
        hr += ph[0]; hz += ph[RNN]; hn += ph[2 * RNN];
    }
    const float r = 1.f / (1.f + expf(-(ir + hr)));
    const float z = 1.f / (1.f + expf(-(iz + hz)));
    const float n = tanhf(in_ + r * hn);
    const float res = (1.f - z) * n + z * h_prev[idx] + x_in[idx];
    out0[idx] = res;
    if (out1) out1[idx] = res;
}

// ---------------------------------------------------------------------------
extern "C" void kernel_launch(void* const* d_in, const int* in_sizes, int n_in,
                              void* d_out, int out_size, void* d_ws, size_t ws_size,
                              hipStream_t stream) {
    const float* x       = (const float*)d_in[0];
    const float* w       = (const float*)d_in[1];
    const float* h_att   = (const float*)d_in[2];
    const float* h_dec0  = (const float*)d_in[3];
    const float* h_dec1  = (const float*)d_in[4];
    const float* memory  = (const float*)d_in[5];
    const float* pre_w1  = (const float*)d_in[6];
    const float* pre_b1  = (const float*)d_in[7];
    const float* pre_w2  = (const float*)d_in[8];
    const float* pre_b2  = (const float*)d_in[9];
    const float* att_wi  = (const float*)d_in[10];
    const float* att_wh  = (const float*)d_in[11];
    const float* att_bi  = (const float*)d_in[12];
    const float* att_bh  = (const float*)d_in[13];
    const float* q_w     = (const float*)d_in[14];
    const float* q_b     = (const float*)d_in[15];
    const float* dec0_wi = (const float*)d_in[16];
    const float* dec0_wh = (const float*)d_in[17];
    const float* dec0_bi = (const float*)d_in[18];
    const float* dec0_bh = (const float*)d_in[19];
    const float* dec1_wi = (const float*)d_in[20];
    const float* dec1_wh = (const float*)d_in[21];
    const float* dec1_bi = (const float*)d_in[22];
    const float* dec1_bh = (const float*)d_in[23];

    float* out = (float*)d_out;
    float* o_h1a = out;                    // h1        (256*768)
    float* o_wn  = out + 196608;           // w_new     (256*512)
    float* o_ha  = out + 327680;           // h_att_new (256*256)
    float* o_h0  = out + 393216;           // h0        (256*768)
    float* o_h1b = out + 589824;           // h1 again  (256*768)

    float* ws    = (float*)d_ws;
    float* q     = ws;                     // 131072
    float* e     = ws + 131072;            // 131072
    float* x_dec = ws + 262144;            // 196608
    float* ctxp  = ws + 458752;            // 1048576   (8 slices x B x 512)
    float* parts = ws + 1507328;           // 4718592   (8 x B x G3)

    front_kernel<<<B / 4, 256, 0, stream>>>(x, pre_w1, pre_b1, pre_w2, pre_b2,
                                            h_att, att_wi, att_wh, att_bi, att_bh,
                                            q_w, q_b, o_ha, x_dec, q);
    mempass_kernel<<<dim3(8, B), 256, 0, stream>>>(memory, w, q, e, ctxp);
    mid_kernel<<<768, 256, 0, stream>>>(ctxp, x_dec, e, w, o_wn);

    gemm_splitk_kernel<<<dim3(G3 / GBN, B / GBM, 8), 256, 0, stream>>>(
        x_dec, h_dec0, dec0_wi, dec0_wh, parts);
    gru_reduce_kernel<<<768, 256, 0, stream>>>(parts, x_dec, h_dec0, dec0_bi, dec0_bh, o_h0, nullptr);

    gemm_splitk_kernel<<<dim3(G3 / GBN, B / GBM, 8), 256, 0, stream>>>(
        o_h0, h_dec1, dec1_wi, dec1_wh, parts);
    gru_reduce_kernel<<<768, 256, 0, stream>>>(parts, o_h0, h_dec1, dec1_bi, dec1_bh, o_h1a, o_h1b);
}

// Round 3
// 249.316 us; speedup vs baseline: 1.1505x; 1.1505x over previous
//
#include <hip/hip_runtime.h>
#include <math.h>

// Sizes (fixed for this problem)
#define B    256
#define T    512
#define CTX  512
#define MEL  160
#define PRE  128
#define ATT  256
#define RNN  768
#define G3   2304   // 3*RNN

typedef __attribute__((ext_vector_type(8))) short short8;
typedef __attribute__((ext_vector_type(4))) float f32x4;

__device__ inline unsigned short f2bf(float f) {
    unsigned u = __float_as_uint(f);
    unsigned r = (u + 0x7fffu + ((u >> 16) & 1u)) >> 16;
    return (unsigned short)r;
}
__device__ inline float bf2f(unsigned short h) {
    return __uint_as_float((unsigned)h << 16);
}

// ---------------------------------------------------------------------------
// Fused front: PreNet -> attention GRUCell -> q projection
// grid: 64 blocks (4 batches each), 256 threads
// ---------------------------------------------------------------------------
__global__ __launch_bounds__(256) void front_kernel(
        const float* __restrict__ x,
        const float* __restrict__ pre_w1, const float* __restrict__ pre_b1,
        const float* __restrict__ pre_w2, const float* __restrict__ pre_b2,
        const float* __restrict__ h_att,
        const float* __restrict__ wi, const float* __restrict__ wh,
        const float* __restrict__ bi, const float* __restrict__ bh,
        const float* __restrict__ qw, const float* __restrict__ qb,
        float* __restrict__ h_att_out, float* __restrict__ x_dec,
        float* __restrict__ q) {
    __shared__ float xf[4][MEL];
    __shared__ float h1[4][PRE];
    __shared__ float hp[4][PRE];
    __shared__ float ha[4][ATT];
    __shared__ float ha2[4][ATT];
    const int tid = threadIdx.x;
    const int b0 = blockIdx.x * 4;

    for (int i = tid; i < 4 * MEL; i += 256) xf[i / MEL][i % MEL] = x[b0 * MEL + i];
    for (int i = tid; i < 4 * ATT; i += 256) ha[i >> 8][i & 255] = h_att[b0 * ATT + i];
    __syncthreads();

    #pragma unroll
    for (int it = 0; it < 2; ++it) {
        const int oid = tid + it * 256;
        const int bl = oid >> 7, j = oid & 127;
        float a = pre_b1[j];
        const float* wr = pre_w1 + (size_t)j * MEL;
        #pragma unroll 4
        for (int k = 0; k < MEL; ++k) a += xf[bl][k] * wr[k];
        h1[bl][j] = fmaxf(a, 0.f);
    }
    __syncthreads();
    #pragma unroll
    for (int it = 0; it < 2; ++it) {
        const int oid = tid + it * 256;
        const int bl = oid >> 7, j = oid & 127;
        float a = pre_b2[j];
        const float* wr = pre_w2 + (size_t)j * PRE;
        #pragma unroll 4
        for (int k = 0; k < PRE; ++k) a += h1[bl][k] * wr[k];
        hp[bl][j] = fmaxf(a, 0.f);
    }
    __syncthreads();

    {
        const int j = tid;
        float gr[4], gz[4], gn[4], hr[4], hz[4], hn[4];
        const float bir = bi[j], biz = bi[ATT + j], bin = bi[2 * ATT + j];
        const float bhr = bh[j], bhz = bh[ATT + j], bhn = bh[2 * ATT + j];
        #pragma unroll
        for (int qq = 0; qq < 4; ++qq) { gr[qq] = bir; gz[qq] = biz; gn[qq] = bin; hr[qq] = bhr; hz[qq] = bhz; hn[qq] = bhn; }
        const float* wir = wi + (size_t)j * PRE;
        const float* wiz = wi + (size_t)(ATT + j) * PRE;
        const float* win = wi + (size_t)(2 * ATT + j) * PRE;
        for (int k = 0; k < PRE; ++k) {
            const float a = wir[k], c = wiz[k], d = win[k];
            #pragma unroll
            for (int qq = 0; qq < 4; ++qq) { const float h_ = hp[qq][k]; gr[qq] += a * h_; gz[qq] += c * h_; gn[qq] += d * h_; }
        }
        const float* whr = wh + (size_t)j * ATT;
        const float* whz = wh + (size_t)(ATT + j) * ATT;
        const float* whn = wh + (size_t)(2 * ATT + j) * ATT;
        for (int k = 0; k < ATT; ++k) {
            const float a = whr[k], c = whz[k], d = whn[k];
            #pragma unroll
            for (int qq = 0; qq < 4; ++qq) { const float h_ = ha[qq][k]; hr[qq] += a * h_; hz[qq] += c * h_; hn[qq] += d * h_; }
        }
        #pragma unroll
        for (int qq = 0; qq < 4; ++qq) {
            const float r = 1.f / (1.f + expf(-(gr[qq] + hr[qq])));
            const float z = 1.f / (1.f + expf(-(gz[qq] + hz[qq])));
            const float n = tanhf(gn[qq] + r * hn[qq]);
            const float hnew = (1.f - z) * n + z * ha[qq][j];
            ha2[qq][j] = hnew;
            h_att_out[(size_t)(b0 + qq) * ATT + j] = hnew;
            x_dec[(size_t)(b0 + qq) * RNN + j] = hnew;
        }
    }
    __syncthreads();

    #pragma unroll
    for (int it = 0; it < 8; ++it) {
        const int oid = tid + it * 256;
        const int bl = oid >> 9, c = oid & 511;
        float a = qb[c];
        const float* wr = qw + (size_t)c * ATT;
        #pragma unroll 4
        for (int k = 0; k < ATT; ++k) a += ha2[bl][k] * wr[k];
        q[(size_t)(b0 + bl) * CTX + c] = a;
    }
}

// ---------------------------------------------------------------------------
// Fused memory pass (single read of memory): e scores + ctx partials
// grid: dim3(8, B), 256 threads
// ---------------------------------------------------------------------------
__global__ void mempass_kernel(const float* __restrict__ mem, const float* __restrict__ w,
                               const float* __restrict__ q, float* __restrict__ e,
                               float* __restrict__ ctx_part) {
    const int b = blockIdx.y, slice = blockIdx.x;
    const int tid = threadIdx.x;
    const int wave = tid >> 6, lane = tid & 63;
    __shared__ float qs[CTX];
    __shared__ float ctx_s[4][CTX];
    for (int i = tid; i < CTX; i += 256) qs[i] = q[(size_t)b * CTX + i];
    __syncthreads();

    const int c0 = lane * 4;
    const int c1 = 256 + lane * 4;
    const float q0 = qs[c0], q1 = qs[c0 + 1], q2 = qs[c0 + 2], q3 = qs[c0 + 3];
    const float q4 = qs[c1], q5 = qs[c1 + 1], q6 = qs[c1 + 2], q7 = qs[c1 + 3];

    const float* mb = mem + (size_t)b * T * CTX;
    float acc[8] = {0.f, 0.f, 0.f, 0.f, 0.f, 0.f, 0.f, 0.f};
    const float invs = 0.04419417382415922f;  // 1/sqrt(512)
    const int t0 = slice * 64 + wave * 16;

    for (int i = 0; i < 16; ++i) {
        const int t = t0 + i;
        const float* row = mb + (size_t)t * CTX;
        const float4 m0 = *(const float4*)(row + c0);
        const float4 m1 = *(const float4*)(row + c1);
        const float wt = w[(size_t)b * T + t];
        float ep = m0.x * q0 + m0.y * q1 + m0.z * q2 + m0.w * q3
                 + m1.x * q4 + m1.y * q5 + m1.z * q6 + m1.w * q7;
        #pragma unroll
        for (int off = 32; off; off >>= 1) ep += __shfl_xor(ep, off);
        if (lane == 0) e[(size_t)b * T + t] = ep * invs;
        acc[0] += wt * m0.x; acc[1] += wt * m0.y; acc[2] += wt * m0.z; acc[3] += wt * m0.w;
        acc[4] += wt * m1.x; acc[5] += wt * m1.y; acc[6] += wt * m1.z; acc[7] += wt * m1.w;
    }
    ctx_s[wave][c0] = acc[0]; ctx_s[wave][c0 + 1] = acc[1]; ctx_s[wave][c0 + 2] = acc[2]; ctx_s[wave][c0 + 3] = acc[3];
    ctx_s[wave][c1] = acc[4]; ctx_s[wave][c1 + 1] = acc[5]; ctx_s[wave][c1 + 2] = acc[6]; ctx_s[wave][c1 + 3] = acc[7];
    __syncthreads();
    for (int c = tid; c < CTX; c += 256) {
        const float s = ctx_s[0][c] + ctx_s[1][c] + ctx_s[2][c] + ctx_s[3][c];
        ctx_part[((size_t)slice * B + b) * CTX + c] = s;
    }
}

// ---------------------------------------------------------------------------
// Fused mid: blocks 0..511 reduce ctx partials -> x_dec[:, 256:768]
//            blocks 512..767 softmax * Markov prior -> w_new
// ---------------------------------------------------------------------------
__global__ void mid_kernel(const float* __restrict__ part, float* __restrict__ x_dec,
                           const float* __restrict__ e, const float* __restrict__ w,
                           float* __restrict__ w_new) {
    const int tid = threadIdx.x;
    if (blockIdx.x < 512) {
        const int idx = blockIdx.x * 256 + tid;
        const int b = idx >> 9, c = idx & 511;
        float s = 0.f;
        #pragma unroll
        for (int sl = 0; sl < 8; ++sl) s += part[((size_t)sl * B + b) * CTX + c];
        x_dec[(size_t)b * RNN + ATT + c] = s;
        return;
    }
    const int b = blockIdx.x - 512;
    const int lane = tid & 63, wv = tid >> 6;
    __shared__ float red[4];
    const float* eb = e + (size_t)b * T;
    const float* wb = w + (size_t)b * T;
    const float e0 = eb[tid], e1 = eb[tid + 256];

    float m = fmaxf(e0, e1);
    #pragma unroll
    for (int o = 32; o; o >>= 1) m = fmaxf(m, __shfl_xor(m, o));
    if (lane == 0) red[wv] = m;
    __syncthreads();
    m = fmaxf(fmaxf(red[0], red[1]), fmaxf(red[2], red[3]));
    __syncthreads();

    const float x0 = expf(e0 - m), x1 = expf(e1 - m);
    float s = x0 + x1;
    #pragma unroll
    for (int o = 32; o; o >>= 1) s += __shfl_xor(s, o);
    if (lane == 0) red[wv] = s;
    __syncthreads();
    s = red[0] + red[1] + red[2] + red[3];
    __syncthreads();

    const float p0 = 0.5f * (wb[tid] + (tid > 0 ? wb[tid - 1] : 0.f));
    const float p1 = 0.5f * (wb[tid + 256] + wb[tid + 255]);
    const float m0 = (x0 / s) * p0;
    const float m1 = (x1 / s) * p1;
    float s2 = m0 + m1;
    #pragma unroll
    for (int o = 32; o; o >>= 1) s2 += __shfl_xor(s2, o);
    if (lane == 0) red[wv] = s2;
    __syncthreads();
    s2 = red[0] + red[1] + red[2] + red[3];
    const float inv = 1.f / (s2 + 1e-8f);
    w_new[(size_t)b * T + tid] = m0 * inv;
    w_new[(size_t)b * T + tid + 256] = m1 * inv;
}

// ---------------------------------------------------------------------------
// bf16-MFMA split-precision GEMM: C[256,2304] = A[256,768] @ W[2304,768]^T
// C = Ah*Wh + Al*Wh + Ah*Wl  (hi/lo bf16 decomposition of fp32, err ~2^-16)
// 64x64 tile, BK=64, 256 thr = 4 waves in 2x2; mfma_f32_16x16x32_bf16.
// LDS in fragment-linear slot layout: slot (sub, lane) holds 8 contiguous
// k-elems of one row; slot = (ms*2+ks)*64 + lane; conflict-free b128 r/w.
// blockIdx.z: 0 -> gi (A=x_in, W=wi), 1 -> gh (A=h_prev, W=wh)
// ---------------------------------------------------------------------------
__global__ __launch_bounds__(256) void mfma_gemm_kernel(
        const float* __restrict__ Agi, const float* __restrict__ Agh,
        const float* __restrict__ Wgi, const float* __restrict__ Wgh,
        float* __restrict__ Cgi, float* __restrict__ Cgh) {
    const int mat = blockIdx.z;
    const float* __restrict__ A = mat ? Agh : Agi;
    const float* __restrict__ W = mat ? Wgh : Wgi;
    float* __restrict__ C = mat ? Cgh : Cgi;

    const int m0 = blockIdx.y * 64;
    const int n0 = blockIdx.x * 64;

    __shared__ __align__(16) short AH[4096];  // 8 subtiles x 64 lanes x 8 bf16
    __shared__ __align__(16) short AL[4096];
    __shared__ __align__(16) short WH[4096];
    __shared__ __align__(16) short WL[4096];

    const int tid = threadIdx.x;
    const int lane = tid & 63;
    const int wave = tid >> 6;
    const int wm = wave >> 1, wn = wave & 1;

    f32x4 acc[2][2] = {{{0.f, 0.f, 0.f, 0.f}, {0.f, 0.f, 0.f, 0.f}},
                       {{0.f, 0.f, 0.f, 0.f}, {0.f, 0.f, 0.f, 0.f}}};

    for (int k0 = 0; k0 < RNN; k0 += 64) {
        // stage A and W (fp32 -> bf16 hi/lo) into fragment-linear LDS
        #pragma unroll
        for (int si = 0; si < 2; ++si) {
            const int s = tid + si * 256;        // slot 0..511
            const int sub = s >> 6;              // ms*2+ks
            const int ln = s & 63;
            const int row = (sub >> 1) * 16 + (ln & 15);
            const int kk = (sub & 1) * 32 + (ln >> 4) * 8;

            const float* ap = A + (size_t)(m0 + row) * RNN + k0 + kk;
            const float4 a0 = *(const float4*)ap;
            const float4 a1 = *(const float4*)(ap + 4);
            const float av[8] = {a0.x, a0.y, a0.z, a0.w, a1.x, a1.y, a1.z, a1.w};
            short hi[8], lo[8];
            #pragma unroll
            for (int u = 0; u < 8; ++u) {
                const unsigned short h = f2bf(av[u]);
                hi[u] = (short)h;
                lo[u] = (short)f2bf(av[u] - bf2f(h));
            }
            *(short8*)&AH[s * 8] = *(const short8*)hi;
            *(short8*)&AL[s * 8] = *(const short8*)lo;

            const float* wp = W + (size_t)(n0 + row) * RNN + k0 + kk;
            const float4 w0 = *(const float4*)wp;
            const float4 w1 = *(const float4*)(wp + 4);
            const float wv[8] = {w0.x, w0.y, w0.z, w0.w, w1.x, w1.y, w1.z, w1.w};
            #pragma unroll
            for (int u = 0; u < 8; ++u) {
                const unsigned short h = f2bf(wv[u]);
                hi[u] = (short)h;
                lo[u] = (short)f2bf(wv[u] - bf2f(h));
            }
            *(short8*)&WH[s * 8] = *(const short8*)hi;
            *(short8*)&WL[s * 8] = *(const short8*)lo;
        }
        __syncthreads();

        #pragma unroll
        for (int ks = 0; ks < 2; ++ks) {
            short8 ah[2], al[2], wh[2], wl[2];
            #pragma unroll
            for (int i = 0; i < 2; ++i) {
                const int asub = ((wm * 2 + i) * 2 + ks);
                ah[i] = *(const short8*)&AH[(asub * 64 + lane) * 8];
                al[i] = *(const short8*)&AL[(asub * 64 + lane) * 8];
                const int wsub = ((wn * 2 + i) * 2 + ks);
                wh[i] = *(const short8*)&WH[(wsub * 64 + lane) * 8];
                wl[i] = *(const short8*)&WL[(wsub * 64 + lane) * 8];
            }
            #pragma unroll
            for (int i = 0; i < 2; ++i)
                #pragma unroll
                for (int j = 0; j < 2; ++j) {
                    acc[i][j] = __builtin_amdgcn_mfma_f32_16x16x32_bf16(ah[i], wh[j], acc[i][j], 0, 0, 0);
                    acc[i][j] = __builtin_amdgcn_mfma_f32_16x16x32_bf16(al[i], wh[j], acc[i][j], 0, 0, 0);
                    acc[i][j] = __builtin_amdgcn_mfma_f32_16x16x32_bf16(ah[i], wl[j], acc[i][j], 0, 0, 0);
                }
        }
        __syncthreads();
    }

    // C/D mapping (m89-verified): col = lane&15, row = (lane>>4)*4 + reg
    const int rowq = lane >> 4, col = lane & 15;
    #pragma unroll
    for (int i = 0; i < 2; ++i)
        #pragma unroll
        for (int j = 0; j < 2; ++j) {
            const int rbase = m0 + wm * 32 + i * 16 + rowq * 4;
            const int cidx = n0 + wn * 32 + j * 16 + col;
            #pragma unroll
            for (int r = 0; r < 4; ++r)
                C[(size_t)(rbase + r) * G3 + cidx] = acc[i][j][r];
        }
}

// ---------------------------------------------------------------------------
// GRU epilogue: bias + gates + residual. grid: 768 blocks x 256 thr
// ---------------------------------------------------------------------------
__global__ void gru_res_kernel(const float* __restrict__ gi, const float* __restrict__ gh,
                               const float* __restrict__ x_in, const float* __restrict__ h_prev,
                               const float* __restrict__ bi, const float* __restrict__ bh,
                               float* __restrict__ out0, float* __restrict__ out1) {
    const int idx = blockIdx.x * 256 + threadIdx.x;
    const int b = idx / RNN, j = idx % RNN;
    const float* gib = gi + (size_t)b * G3;
    const float* ghb = gh + (size_t)b * G3;
    const float ir = gib[j] + bi[j];
    const float iz = gib[RNN + j] + bi[RNN + j];
    const float in_ = gib[2 * RNN + j] + bi[2 * RNN + j];
    const float hr = ghb[j] + bh[j];
    const float hz = ghb[RNN + j] + bh[RNN + j];
    const float hn = ghb[2 * RNN + j] + bh[2 * RNN + j];
    const float r = 1.f / (1.f + expf(-(ir + hr)));
    const float z = 1.f / (1.f + expf(-(iz + hz)));
    const float n = tanhf(in_ + r * hn);
    const float res = (1.f - z) * n + z * h_prev[idx] + x_in[idx];
    out0[idx] = res;
    if (out1) out1[idx] = res;
}

// ---------------------------------------------------------------------------
extern "C" void kernel_launch(void* const* d_in, const int* in_sizes, int n_in,
                              void* d_out, int out_size, void* d_ws, size_t ws_size,
                              hipStream_t stream) {
    const float* x       = (const float*)d_in[0];
    const float* w       = (const float*)d_in[1];
    const float* h_att   = (const float*)d_in[2];
    const float* h_dec0  = (const float*)d_in[3];
    const float* h_dec1  = (const float*)d_in[4];
    const float* memory  = (const float*)d_in[5];
    const float* pre_w1  = (const float*)d_in[6];
    const float* pre_b1  = (const float*)d_in[7];
    const float* pre_w2  = (const float*)d_in[8];
    const float* pre_b2  = (const float*)d_in[9];
    const float* att_wi  = (const float*)d_in[10];
    const float* att_wh  = (const float*)d_in[11];
    const float* att_bi  = (const float*)d_in[12];
    const float* att_bh  = (const float*)d_in[13];
    const float* q_w     = (const float*)d_in[14];
    const float* q_b     = (const float*)d_in[15];
    const float* dec0_wi = (const float*)d_in[16];
    const float* dec0_wh = (const float*)d_in[17];
    const float* dec0_bi = (const float*)d_in[18];
    const float* dec0_bh = (const float*)d_in[19];
    const float* dec1_wi = (const float*)d_in[20];
    const float* dec1_wh = (const float*)d_in[21];
    const float* dec1_bi = (const float*)d_in[22];
    const float* dec1_bh = (const float*)d_in[23];

    float* out = (float*)d_out;
    float* o_h1a = out;                    // h1        (256*768)
    float* o_wn  = out + 196608;           // w_new     (256*512)
    float* o_ha  = out + 327680;           // h_att_new (256*256)
    float* o_h0  = out + 393216;           // h0        (256*768)
    float* o_h1b = out + 589824;           // h1 again  (256*768)

    float* ws    = (float*)d_ws;
    float* q     = ws;                     // 131072
    float* e     = ws + 131072;            // 131072
    float* x_dec = ws + 262144;            // 196608
    float* ctxp  = ws + 458752;            // 1048576  (8 slices x B x 512)
    float* gi    = ws + 1507328;           // 589824
    float* gh    = ws + 2097152;           // 589824

    front_kernel<<<B / 4, 256, 0, stream>>>(x, pre_w1, pre_b1, pre_w2, pre_b2,
                                            h_att, att_wi, att_wh, att_bi, att_bh,
                                            q_w, q_b, o_ha, x_dec, q);
    mempass_kernel<<<dim3(8, B), 256, 0, stream>>>(memory, w, q, e, ctxp);
    mid_kernel<<<768, 256, 0, stream>>>(ctxp, x_dec, e, w, o_wn);

    mfma_gemm_kernel<<<dim3(G3 / 64, B / 64, 2), 256, 0, stream>>>(
        x_dec, h_dec0, dec0_wi, dec0_wh, gi, gh);
    gru_res_kernel<<<768, 256, 0, stream>>>(gi, gh, x_dec, h_dec0, dec0_bi, dec0_bh, o_h0, nullptr);

    mfma_gemm_kernel<<<dim3(G3 / 64, B / 64, 2), 256, 0, stream>>>(
        o_h0, h_dec1, dec1_wi, dec1_wh, gi, gh);
    gru_res_kernel<<<768, 256, 0, stream>>>(gi, gh, o_h0, h_dec1, dec1_bi, dec1_bh, o_h1a, o_h1b);
}

// Round 4
// 191.570 us; speedup vs baseline: 1.4973x; 1.3014x over previous
//
#include <hip/hip_runtime.h>
#include <math.h>

// Sizes (fixed for this problem)
#define B    256
#define T    512
#define CTX  512
#define MEL  160
#define PRE  128
#define ATT  256
#define RNN  768
#define G3   2304   // 3*RNN

typedef __attribute__((ext_vector_type(8))) short short8;
typedef __attribute__((ext_vector_type(4))) float f32x4;

__device__ inline unsigned short f2bf(float f) {
    unsigned u = __float_as_uint(f);
    unsigned r = (u + 0x7fffu + ((u >> 16) & 1u)) >> 16;
    return (unsigned short)r;
}
__device__ inline float bf2f(unsigned short h) {
    return __uint_as_float((unsigned)h << 16);
}

// ---------------------------------------------------------------------------
// Transpose the small front weights so front_kernel reads are coalesced.
// wit[k][j] (128x768), wht[k][j] (256x768), qwt[k][j] (256x512),
// p1t[k][j] (160x128), p2t[k][j] (128x128)
// grid: 1808 x 256 (462848 elements total)
// ---------------------------------------------------------------------------
__global__ void wtrans_kernel(const float* __restrict__ wi, const float* __restrict__ wh,
                              const float* __restrict__ qw, const float* __restrict__ pw1,
                              const float* __restrict__ pw2,
                              float* __restrict__ wit, float* __restrict__ wht,
                              float* __restrict__ qwt, float* __restrict__ p1t,
                              float* __restrict__ p2t) {
    int idx = blockIdx.x * 256 + threadIdx.x;
    if (idx < 98304)  { const int j = idx % 768; const int k = idx / 768; wit[idx] = wi[j * 128 + k]; return; }
    idx -= 98304;
    if (idx < 196608) { const int j = idx % 768; const int k = idx / 768; wht[idx] = wh[j * 256 + k]; return; }
    idx -= 196608;
    if (idx < 131072) { const int j = idx % 512; const int k = idx / 512; qwt[idx] = qw[j * 256 + k]; return; }
    idx -= 131072;
    if (idx < 20480)  { const int j = idx % 128; const int k = idx / 128; p1t[idx] = pw1[j * 160 + k]; return; }
    idx -= 20480;
    if (idx < 16384)  { const int j = idx % 128; const int k = idx / 128; p2t[idx] = pw2[j * 128 + k]; }
}

// ---------------------------------------------------------------------------
// Fused front: PreNet -> attention GRUCell -> q projection
// grid: 64 blocks (4 batches each), 256 threads
// All weight reads lane-coalesced via transposed weights; activations via LDS
// broadcast.
// ---------------------------------------------------------------------------
__global__ __launch_bounds__(256) void front_kernel(
        const float* __restrict__ x,
        const float* __restrict__ p1t, const float* __restrict__ pre_b1,
        const float* __restrict__ p2t, const float* __restrict__ pre_b2,
        const float* __restrict__ h_att,
        const float* __restrict__ wit, const float* __restrict__ wht,
        const float* __restrict__ bi, const float* __restrict__ bh,
        const float* __restrict__ qwt, const float* __restrict__ qb,
        float* __restrict__ h_att_out, float* __restrict__ x_dec,
        float* __restrict__ q) {
    __shared__ float xf[4][MEL];
    __shared__ float h1s[4][PRE];
    __shared__ float hps[4][PRE];
    __shared__ float ha[4][ATT];
    __shared__ float ha2[4][ATT];
    const int tid = threadIdx.x;
    const int b0 = blockIdx.x * 4;

    for (int i = tid; i < 4 * MEL; i += 256) xf[i / MEL][i % MEL] = x[b0 * MEL + i];
    for (int i = tid; i < 4 * ATT; i += 256) ha[i >> 8][i & 255] = h_att[b0 * ATT + i];
    __syncthreads();

    // PreNet layer 1: thread = (batch-pair bp, out j); W^T rows coalesced
    {
        const int j = tid & 127, bp = tid >> 7;
        float a0 = pre_b1[j], a1 = a0;
        for (int k = 0; k < MEL; ++k) {
            const float wv = p1t[k * PRE + j];
            a0 += wv * xf[bp * 2][k];
            a1 += wv * xf[bp * 2 + 1][k];
        }
        h1s[bp * 2][j]     = fmaxf(a0, 0.f);
        h1s[bp * 2 + 1][j] = fmaxf(a1, 0.f);
    }
    __syncthreads();
    // PreNet layer 2
    {
        const int j = tid & 127, bp = tid >> 7;
        float a0 = pre_b2[j], a1 = a0;
        for (int k = 0; k < PRE; ++k) {
            const float wv = p2t[k * PRE + j];
            a0 += wv * h1s[bp * 2][k];
            a1 += wv * h1s[bp * 2 + 1][k];
        }
        hps[bp * 2][j]     = fmaxf(a0, 0.f);
        hps[bp * 2 + 1][j] = fmaxf(a1, 0.f);
    }
    __syncthreads();

    // attention GRU: thread = output feature j (0..255), 4 batches in regs
    {
        const int j = tid;
        float gr[4], gz[4], gn[4], hr[4], hz[4], hn[4];
        const float bir = bi[j], biz = bi[ATT + j], bin = bi[2 * ATT + j];
        const float bhr = bh[j], bhz = bh[ATT + j], bhn = bh[2 * ATT + j];
        #pragma unroll
        for (int qq = 0; qq < 4; ++qq) { gr[qq] = bir; gz[qq] = biz; gn[qq] = bin; hr[qq] = bhr; hz[qq] = bhz; hn[qq] = bhn; }
        for (int k = 0; k < PRE; ++k) {
            const float a = wit[k * 768 + j];
            const float c = wit[k * 768 + 256 + j];
            const float d = wit[k * 768 + 512 + j];
            #pragma unroll
            for (int qq = 0; qq < 4; ++qq) { const float h_ = hps[qq][k]; gr[qq] += a * h_; gz[qq] += c * h_; gn[qq] += d * h_; }
        }
        for (int k = 0; k < ATT; ++k) {
            const float a = wht[k * 768 + j];
            const float c = wht[k * 768 + 256 + j];
            const float d = wht[k * 768 + 512 + j];
            #pragma unroll
            for (int qq = 0; qq < 4; ++qq) { const float h_ = ha[qq][k]; hr[qq] += a * h_; hz[qq] += c * h_; hn[qq] += d * h_; }
        }
        #pragma unroll
        for (int qq = 0; qq < 4; ++qq) {
            const float r = 1.f / (1.f + expf(-(gr[qq] + hr[qq])));
            const float z = 1.f / (1.f + expf(-(gz[qq] + hz[qq])));
            const float n = tanhf(gn[qq] + r * hn[qq]);
            const float hnew = (1.f - z) * n + z * ha[qq][j];
            ha2[qq][j] = hnew;
            h_att_out[(size_t)(b0 + qq) * ATT + j] = hnew;
            x_dec[(size_t)(b0 + qq) * RNN + j] = hnew;
        }
    }
    __syncthreads();

    // q projection: thread = cols tid and tid+256, 4 batches
    {
        float a0[4], a1[4];
        const float qb0 = qb[tid], qb1 = qb[tid + 256];
        #pragma unroll
        for (int qq = 0; qq < 4; ++qq) { a0[qq] = qb0; a1[qq] = qb1; }
        for (int k = 0; k < ATT; ++k) {
            const float w0 = qwt[k * 512 + tid];
            const float w1 = qwt[k * 512 + 256 + tid];
            #pragma unroll
            for (int qq = 0; qq < 4; ++qq) {
                const float hv = ha2[qq][k];
                a0[qq] += w0 * hv;
                a1[qq] += w1 * hv;
            }
        }
        #pragma unroll
        for (int qq = 0; qq < 4; ++qq) {
            q[(size_t)(b0 + qq) * CTX + tid]       = a0[qq];
            q[(size_t)(b0 + qq) * CTX + tid + 256] = a1[qq];
        }
    }
}

// ---------------------------------------------------------------------------
// Fused memory pass (single read of memory): e scores + ctx partials
// grid: dim3(8, B), 256 threads
// ---------------------------------------------------------------------------
__global__ void mempass_kernel(const float* __restrict__ mem, const float* __restrict__ w,
                               const float* __restrict__ q, float* __restrict__ e,
                               float* __restrict__ ctx_part) {
    const int b = blockIdx.y, slice = blockIdx.x;
    const int tid = threadIdx.x;
    const int wave = tid >> 6, lane = tid & 63;
    __shared__ float qs[CTX];
    __shared__ float ctx_s[4][CTX];
    for (int i = tid; i < CTX; i += 256) qs[i] = q[(size_t)b * CTX + i];
    __syncthreads();

    const int c0 = lane * 4;
    const int c1 = 256 + lane * 4;
    const float q0 = qs[c0], q1 = qs[c0 + 1], q2 = qs[c0 + 2], q3 = qs[c0 + 3];
    const float q4 = qs[c1], q5 = qs[c1 + 1], q6 = qs[c1 + 2], q7 = qs[c1 + 3];

    const float* mb = mem + (size_t)b * T * CTX;
    float acc[8] = {0.f, 0.f, 0.f, 0.f, 0.f, 0.f, 0.f, 0.f};
    const float invs = 0.04419417382415922f;  // 1/sqrt(512)
    const int t0 = slice * 64 + wave * 16;

    for (int i = 0; i < 16; ++i) {
        const int t = t0 + i;
        const float* row = mb + (size_t)t * CTX;
        const float4 m0 = *(const float4*)(row + c0);
        const float4 m1 = *(const float4*)(row + c1);
        const float wt = w[(size_t)b * T + t];
        float ep = m0.x * q0 + m0.y * q1 + m0.z * q2 + m0.w * q3
                 + m1.x * q4 + m1.y * q5 + m1.z * q6 + m1.w * q7;
        #pragma unroll
        for (int off = 32; off; off >>= 1) ep += __shfl_xor(ep, off);
        if (lane == 0) e[(size_t)b * T + t] = ep * invs;
        acc[0] += wt * m0.x; acc[1] += wt * m0.y; acc[2] += wt * m0.z; acc[3] += wt * m0.w;
        acc[4] += wt * m1.x; acc[5] += wt * m1.y; acc[6] += wt * m1.z; acc[7] += wt * m1.w;
    }
    ctx_s[wave][c0] = acc[0]; ctx_s[wave][c0 + 1] = acc[1]; ctx_s[wave][c0 + 2] = acc[2]; ctx_s[wave][c0 + 3] = acc[3];
    ctx_s[wave][c1] = acc[4]; ctx_s[wave][c1 + 1] = acc[5]; ctx_s[wave][c1 + 2] = acc[6]; ctx_s[wave][c1 + 3] = acc[7];
    __syncthreads();
    for (int c = tid; c < CTX; c += 256) {
        const float s = ctx_s[0][c] + ctx_s[1][c] + ctx_s[2][c] + ctx_s[3][c];
        ctx_part[((size_t)slice * B + b) * CTX + c] = s;
    }
}

// ---------------------------------------------------------------------------
// Fused mid: blocks 0..511 reduce ctx partials -> x_dec[:, 256:768]
//            blocks 512..767 softmax * Markov prior -> w_new
// ---------------------------------------------------------------------------
__global__ void mid_kernel(const float* __restrict__ part, float* __restrict__ x_dec,
                           const float* __restrict__ e, const float* __restrict__ w,
                           float* __restrict__ w_new) {
    const int tid = threadIdx.x;
    if (blockIdx.x < 512) {
        const int idx = blockIdx.x * 256 + tid;
        const int b = idx >> 9, c = idx & 511;
        float s = 0.f;
        #pragma unroll
        for (int sl = 0; sl < 8; ++sl) s += part[((size_t)sl * B + b) * CTX + c];
        x_dec[(size_t)b * RNN + ATT + c] = s;
        return;
    }
    const int b = blockIdx.x - 512;
    const int lane = tid & 63, wv = tid >> 6;
    __shared__ float red[4];
    const float* eb = e + (size_t)b * T;
    const float* wb = w + (size_t)b * T;
    const float e0 = eb[tid], e1 = eb[tid + 256];

    float m = fmaxf(e0, e1);
    #pragma unroll
    for (int o = 32; o; o >>= 1) m = fmaxf(m, __shfl_xor(m, o));
    if (lane == 0) red[wv] = m;
    __syncthreads();
    m = fmaxf(fmaxf(red[0], red[1]), fmaxf(red[2], red[3]));
    __syncthreads();

    const float x0 = expf(e0 - m), x1 = expf(e1 - m);
    float s = x0 + x1;
    #pragma unroll
    for (int o = 32; o; o >>= 1) s += __shfl_xor(s, o);
    if (lane == 0) red[wv] = s;
    __syncthreads();
    s = red[0] + red[1] + red[2] + red[3];
    __syncthreads();

    const float p0 = 0.5f * (wb[tid] + (tid > 0 ? wb[tid - 1] : 0.f));
    const float p1 = 0.5f * (wb[tid + 256] + wb[tid + 255]);
    const float m0 = (x0 / s) * p0;
    const float m1 = (x1 / s) * p1;
    float s2 = m0 + m1;
    #pragma unroll
    for (int o = 32; o; o >>= 1) s2 += __shfl_xor(s2, o);
    if (lane == 0) red[wv] = s2;
    __syncthreads();
    s2 = red[0] + red[1] + red[2] + red[3];
    const float inv = 1.f / (s2 + 1e-8f);
    w_new[(size_t)b * T + tid] = m0 * inv;
    w_new[(size_t)b * T + tid + 256] = m1 * inv;
}

// ---------------------------------------------------------------------------
// bf16-MFMA split-precision GEMM: C[256,2304] = A[256,768] @ W[2304,768]^T
// C = Ah*Wh + Al*Wh + Ah*Wl  (hi/lo bf16 decomposition of fp32)
// 64x64 tile, BK=64, 4 waves 2x2, mfma_f32_16x16x32_bf16, fragment-linear LDS
// ---------------------------------------------------------------------------
__global__ __launch_bounds__(256) void mfma_gemm_kernel(
        const float* __restrict__ Agi, const float* __restrict__ Agh,
        const float* __restrict__ Wgi, const float* __restrict__ Wgh,
        float* __restrict__ Cgi, float* __restrict__ Cgh) {
    const int mat = blockIdx.z;
    const float* __restrict__ A = mat ? Agh : Agi;
    const float* __restrict__ W = mat ? Wgh : Wgi;
    float* __restrict__ C = mat ? Cgh : Cgi;

    const int m0 = blockIdx.y * 64;
    const int n0 = blockIdx.x * 64;

    __shared__ __align__(16) short AH[4096];
    __shared__ __align__(16) short AL[4096];
    __shared__ __align__(16) short WH[4096];
    __shared__ __align__(16) short WL[4096];

    const int tid = threadIdx.x;
    const int lane = tid & 63;
    const int wave = tid >> 6;
    const int wm = wave >> 1, wn = wave & 1;

    f32x4 acc[2][2] = {{{0.f, 0.f, 0.f, 0.f}, {0.f, 0.f, 0.f, 0.f}},
                       {{0.f, 0.f, 0.f, 0.f}, {0.f, 0.f, 0.f, 0.f}}};

    for (int k0 = 0; k0 < RNN; k0 += 64) {
        #pragma unroll
        for (int si = 0; si < 2; ++si) {
            const int s = tid + si * 256;
            const int sub = s >> 6;
            const int ln = s & 63;
            const int row = (sub >> 1) * 16 + (ln & 15);
            const int kk = (sub & 1) * 32 + (ln >> 4) * 8;

            const float* ap = A + (size_t)(m0 + row) * RNN + k0 + kk;
            const float4 a0 = *(const float4*)ap;
            const float4 a1 = *(const float4*)(ap + 4);
            const float av[8] = {a0.x, a0.y, a0.z, a0.w, a1.x, a1.y, a1.z, a1.w};
            short hi[8], lo[8];
            #pragma unroll
            for (int u = 0; u < 8; ++u) {
                const unsigned short h = f2bf(av[u]);
                hi[u] = (short)h;
                lo[u] = (short)f2bf(av[u] - bf2f(h));
            }
            *(short8*)&AH[s * 8] = *(const short8*)hi;
            *(short8*)&AL[s * 8] = *(const short8*)lo;

            const float* wp = W + (size_t)(n0 + row) * RNN + k0 + kk;
            const float4 w0 = *(const float4*)wp;
            const float4 w1 = *(const float4*)(wp + 4);
            const float wv[8] = {w0.x, w0.y, w0.z, w0.w, w1.x, w1.y, w1.z, w1.w};
            #pragma unroll
            for (int u = 0; u < 8; ++u) {
                const unsigned short h = f2bf(wv[u]);
                hi[u] = (short)h;
                lo[u] = (short)f2bf(wv[u] - bf2f(h));
            }
            *(short8*)&WH[s * 8] = *(const short8*)hi;
            *(short8*)&WL[s * 8] = *(const short8*)lo;
        }
        __syncthreads();

        #pragma unroll
        for (int ks = 0; ks < 2; ++ks) {
            short8 ah[2], al[2], wh[2], wl[2];
            #pragma unroll
            for (int i = 0; i < 2; ++i) {
                const int asub = ((wm * 2 + i) * 2 + ks);
                ah[i] = *(const short8*)&AH[(asub * 64 + lane) * 8];
                al[i] = *(const short8*)&AL[(asub * 64 + lane) * 8];
                const int wsub = ((wn * 2 + i) * 2 + ks);
                wh[i] = *(const short8*)&WH[(wsub * 64 + lane) * 8];
                wl[i] = *(const short8*)&WL[(wsub * 64 + lane) * 8];
            }
            #pragma unroll
            for (int i = 0; i < 2; ++i)
                #pragma unroll
                for (int j = 0; j < 2; ++j) {
                    acc[i][j] = __builtin_amdgcn_mfma_f32_16x16x32_bf16(ah[i], wh[j], acc[i][j], 0, 0, 0);
                    acc[i][j] = __builtin_amdgcn_mfma_f32_16x16x32_bf16(al[i], wh[j], acc[i][j], 0, 0, 0);
                    acc[i][j] = __builtin_amdgcn_mfma_f32_16x16x32_bf16(ah[i], wl[j], acc[i][j], 0, 0, 0);
                }
        }
        __syncthreads();
    }

    const int rowq = lane >> 4, col = lane & 15;
    #pragma unroll
    for (int i = 0; i < 2; ++i)
        #pragma unroll
        for (int j = 0; j < 2; ++j) {
            const int rbase = m0 + wm * 32 + i * 16 + rowq * 4;
            const int cidx = n0 + wn * 32 + j * 16 + col;
            #pragma unroll
            for (int r = 0; r < 4; ++r)
                C[(size_t)(rbase + r) * G3 + cidx] = acc[i][j][r];
        }
}

// ---------------------------------------------------------------------------
// GRU epilogue: bias + gates + residual. grid: 768 blocks x 256 thr
// ---------------------------------------------------------------------------
__global__ void gru_res_kernel(const float* __restrict__ gi, const float* __restrict__ gh,
                               const float* __restrict__ x_in, const float* __restrict__ h_prev,
                               const float* __restrict__ bi, const float* __restrict__ bh,
                               float* __restrict__ out0, float* __restrict__ out1) {
    const int idx = blockIdx.x * 256 + threadIdx.x;
    const int b = idx / RNN, j = idx % RNN;
    const float* gib = gi + (size_t)b * G3;
    const float* ghb = gh + (size_t)b * G3;
    const float ir = gib[j] + bi[j];
    const float iz = gib[RNN + j] + bi[RNN + j];
    const float in_ = gib[2 * RNN + j] + bi[2 * RNN + j];
    const float hr = ghb[j] + bh[j];
    const float hz = ghb[RNN + j] + bh[RNN + j];
    const float hn = ghb[2 * RNN + j] + bh[2 * RNN + j];
    const float r = 1.f / (1.f + expf(-(ir + hr)));
    const float z = 1.f / (1.f + expf(-(iz + hz)));
    const float n = tanhf(in_ + r * hn);
    const float res = (1.f - z) * n + z * h_prev[idx] + x_in[idx];
    out0[idx] = res;
    if (out1) out1[idx] = res;
}

// ---------------------------------------------------------------------------
extern "C" void kernel_launch(void* const* d_in, const int* in_sizes, int n_in,
                              void* d_out, int out_size, void* d_ws, size_t ws_size,
                              hipStream_t stream) {
    const float* x       = (const float*)d_in[0];
    const float* w       = (const float*)d_in[1];
    const float* h_att   = (const float*)d_in[2];
    const float* h_dec0  = (const float*)d_in[3];
    const float* h_dec1  = (const float*)d_in[4];
    const float* memory  = (const float*)d_in[5];
    const float* pre_w1  = (const float*)d_in[6];
    const float* pre_b1  = (const float*)d_in[7];
    const float* pre_w2  = (const float*)d_in[8];
    const float* pre_b2  = (const float*)d_in[9];
    const float* att_wi  = (const float*)d_in[10];
    const float* att_wh  = (const float*)d_in[11];
    const float* att_bi  = (const float*)d_in[12];
    const float* att_bh  = (const float*)d_in[13];
    const float* q_w     = (const float*)d_in[14];
    const float* q_b     = (const float*)d_in[15];
    const float* dec0_wi = (const float*)d_in[16];
    const float* dec0_wh = (const float*)d_in[17];
    const float* dec0_bi = (const float*)d_in[18];
    const float* dec0_bh = (const float*)d_in[19];
    const float* dec1_wi = (const float*)d_in[20];
    const float* dec1_wh = (const float*)d_in[21];
    const float* dec1_bi = (const float*)d_in[22];
    const float* dec1_bh = (const float*)d_in[23];

    float* out = (float*)d_out;
    float* o_h1a = out;                    // h1        (256*768)
    float* o_wn  = out + 196608;           // w_new     (256*512)
    float* o_ha  = out + 327680;           // h_att_new (256*256)
    float* o_h0  = out + 393216;           // h0        (256*768)
    float* o_h1b = out + 589824;           // h1 again  (256*768)

    float* ws    = (float*)d_ws;
    float* q     = ws;                     // 131072
    float* e     = ws + 131072;            // 131072
    float* x_dec = ws + 262144;            // 196608
    float* ctxp  = ws + 458752;            // 1048576  (8 slices x B x 512)
    float* gi    = ws + 1507328;           // 589824
    float* gh    = ws + 2097152;           // 589824
    float* wit   = ws + 2686976;           // 98304   (128 x 768)
    float* wht   = ws + 2785280;           // 196608  (256 x 768)
    float* qwt   = ws + 2981888;           // 131072  (256 x 512)
    float* p1t   = ws + 3112960;           // 20480   (160 x 128)
    float* p2t   = ws + 3133440;           // 16384   (128 x 128)

    wtrans_kernel<<<1808, 256, 0, stream>>>(att_wi, att_wh, q_w, pre_w1, pre_w2,
                                            wit, wht, qwt, p1t, p2t);
    front_kernel<<<B / 4, 256, 0, stream>>>(x, p1t, pre_b1, p2t, pre_b2,
                                            h_att, wit, wht, att_bi, att_bh,
                                            qwt, q_b, o_ha, x_dec, q);
    mempass_kernel<<<dim3(8, B), 256, 0, stream>>>(memory, w, q, e, ctxp);
    mid_kernel<<<768, 256, 0, stream>>>(ctxp, x_dec, e, w, o_wn);

    mfma_gemm_kernel<<<dim3(G3 / 64, B / 64, 2), 256, 0, stream>>>(
        x_dec, h_dec0, dec0_wi, dec0_wh, gi, gh);
    gru_res_kernel<<<768, 256, 0, stream>>>(gi, gh, x_dec, h_dec0, dec0_bi, dec0_bh, o_h0, nullptr);

    mfma_gemm_kernel<<<dim3(G3 / 64, B / 64, 2), 256, 0, stream>>>(
        o_h0, h_dec1, dec1_wi, dec1_wh, gi, gh);
    gru_res_kernel<<<768, 256, 0, stream>>>(gi, gh, o_h0, h_dec1, dec1_bi, dec1_bh, o_h1a, o_h1b);
}

// Round 5
// 185.503 us; speedup vs baseline: 1.5462x; 1.0327x over previous
//
#include <hip/hip_runtime.h>
#include <math.h>

// Sizes (fixed for this problem)
#define B    256
#define T    512
#define CTX  512
#define MEL  160
#define PRE  128
#define ATT  256
#define RNN  768
#define G3   2304   // 3*RNN

typedef __attribute__((ext_vector_type(8))) short short8;
typedef __attribute__((ext_vector_type(4))) float f32x4;

__device__ inline unsigned short f2bf(float f) {
    unsigned u = __float_as_uint(f);
    unsigned r = (u + 0x7fffu + ((u >> 16) & 1u)) >> 16;
    return (unsigned short)r;
}
__device__ inline float bf2f(unsigned short h) {
    return __uint_as_float((unsigned)h << 16);
}

// ---------------------------------------------------------------------------
// wconv: elementwise fp32 -> bf16 hi/lo for the five front weight matrices
// (row-major, no transpose — MFMA B-frags read the original [N][K] layout).
// total 462848 elements; grid 1808 x 256
// ---------------------------------------------------------------------------
__global__ void wconv_kernel(const float* __restrict__ pw1, const float* __restrict__ pw2,
                             const float* __restrict__ wi, const float* __restrict__ wh,
                             const float* __restrict__ qw,
                             short* __restrict__ p1h, short* __restrict__ p1l,
                             short* __restrict__ p2h, short* __restrict__ p2l,
                             short* __restrict__ wih, short* __restrict__ wil,
                             short* __restrict__ whh, short* __restrict__ whl,
                             short* __restrict__ qwh, short* __restrict__ qwl) {
    int idx = blockIdx.x * 256 + threadIdx.x;
    const float* src; short *dh, *dl;
    if (idx < 20480)       { src = pw1; dh = p1h; dl = p1l; }
    else if ((idx -= 20480) < 16384)  { src = pw2; dh = p2h; dl = p2l; }
    else if ((idx -= 16384) < 98304)  { src = wi;  dh = wih; dl = wil; }
    else if ((idx -= 98304) < 196608) { src = wh;  dh = whh; dl = whl; }
    else if ((idx -= 196608) < 131072){ src = qw;  dh = qwh; dl = qwl; }
    else return;
    const float v = src[idx];
    const unsigned short h = f2bf(v);
    dh[idx] = (short)h;
    dl[idx] = (short)f2bf(v - bf2f(h));
}

// ---------------------------------------------------------------------------
// front_mfma: PreNet -> attention GRU -> q projection, all via
// mfma_f32_16x16x32_bf16 with 3-pass hi/lo split precision.
// grid: 16 blocks (16 batches each) x 512 threads (8 waves).
// A-frag layout per 16-row x 32-k subtile: lane l holds row=l&15,
// k = ks*32 + (l>>4)*8 + u (u=0..7). C: col=lane&15, row=(lane>>4)*4+r.
// ---------------------------------------------------------------------------
__global__ __launch_bounds__(512) void front_mfma_kernel(
        const float* __restrict__ x, const float* __restrict__ b1,
        const float* __restrict__ b2, const float* __restrict__ h_att,
        const float* __restrict__ bi, const float* __restrict__ bh,
        const float* __restrict__ qb,
        const short* __restrict__ p1h, const short* __restrict__ p1l,
        const short* __restrict__ p2h, const short* __restrict__ p2l,
        const short* __restrict__ wih, const short* __restrict__ wil,
        const short* __restrict__ whh, const short* __restrict__ whl,
        const short* __restrict__ qwh, const short* __restrict__ qwl,
        float* __restrict__ h_att_out, float* __restrict__ x_dec,
        float* __restrict__ q) {
    __shared__ __align__(16) short AH[8][64][8];   // 8 KB  A-frags hi (K<=256)
    __shared__ __align__(16) short AL[8][64][8];   // 8 KB  A-frags lo
    __shared__ __align__(16) float S[16][RNN];     // 48 KB stage buf (h1/h_pre/gi)
    __shared__ __align__(16) float S2[16][RNN];    // 48 KB gh
    __shared__ __align__(16) float hs[16][ATT];    // 16 KB h_att / h_att_new

    const int tid = threadIdx.x;
    const int wave = tid >> 6, lane = tid & 63;
    const int mb = blockIdx.x * 16;
    const int col = lane & 15, rowq = lane >> 4;

    // load h_att (16x256) and x-frags (K=160, 5 subtiles, 320 slots)
    for (int i = tid; i < 16 * ATT; i += 512)
        hs[i >> 8][i & 255] = h_att[(size_t)(mb + (i >> 8)) * ATT + (i & 255)];
    if (tid < 320) {
        const int sub = tid >> 6, ln = tid & 63;
        const int row = ln & 15, kk = sub * 32 + (ln >> 4) * 8;
        const float* p = x + (size_t)(mb + row) * MEL + kk;
        const float4 v0 = *(const float4*)p;
        const float4 v1 = *(const float4*)(p + 4);
        const float av[8] = {v0.x, v0.y, v0.z, v0.w, v1.x, v1.y, v1.z, v1.w};
        short hi[8], lo[8];
        #pragma unroll
        for (int u = 0; u < 8; ++u) {
            const unsigned short h = f2bf(av[u]);
            hi[u] = (short)h; lo[u] = (short)f2bf(av[u] - bf2f(h));
        }
        *(short8*)AH[sub][ln] = *(const short8*)hi;
        *(short8*)AL[sub][ln] = *(const short8*)lo;
    }
    __syncthreads();

    // ---- prenet layer 1: N=128 (8 ntiles = 8 waves), K=160 (5 subs)
    {
        const int n = wave;
        f32x4 acc = {0.f, 0.f, 0.f, 0.f};
        #pragma unroll
        for (int ks = 0; ks < 5; ++ks) {
            const short8 a_h = *(const short8*)AH[ks][lane];
            const short8 a_l = *(const short8*)AL[ks][lane];
            const size_t off = (size_t)(n * 16 + col) * MEL + ks * 32 + rowq * 8;
            const short8 b_h = *(const short8*)(p1h + off);
            const short8 b_l = *(const short8*)(p1l + off);
            acc = __builtin_amdgcn_mfma_f32_16x16x32_bf16(a_h, b_h, acc, 0, 0, 0);
            acc = __builtin_amdgcn_mfma_f32_16x16x32_bf16(a_l, b_h, acc, 0, 0, 0);
            acc = __builtin_amdgcn_mfma_f32_16x16x32_bf16(a_h, b_l, acc, 0, 0, 0);
        }
        const int j = n * 16 + col;
        const float bb = b1[j];
        #pragma unroll
        for (int r = 0; r < 4; ++r)
            S[rowq * 4 + r][j] = fmaxf(acc[r] + bb, 0.f);
    }
    __syncthreads();
    // frag-convert S[:, 0:128] (K=128, 4 subs, 256 slots)
    if (tid < 256) {
        const int sub = tid >> 6, ln = tid & 63;
        const int row = ln & 15, kk = sub * 32 + (ln >> 4) * 8;
        const float4 v0 = *(const float4*)&S[row][kk];
        const float4 v1 = *(const float4*)&S[row][kk + 4];
        const float av[8] = {v0.x, v0.y, v0.z, v0.w, v1.x, v1.y, v1.z, v1.w};
        short hi[8], lo[8];
        #pragma unroll
        for (int u = 0; u < 8; ++u) {
            const unsigned short h = f2bf(av[u]);
            hi[u] = (short)h; lo[u] = (short)f2bf(av[u] - bf2f(h));
        }
        *(short8*)AH[sub][ln] = *(const short8*)hi;
        *(short8*)AL[sub][ln] = *(const short8*)lo;
    }
    __syncthreads();

    // ---- prenet layer 2: N=128, K=128 (4 subs)
    {
        const int n = wave;
        f32x4 acc = {0.f, 0.f, 0.f, 0.f};
        #pragma unroll
        for (int ks = 0; ks < 4; ++ks) {
            const short8 a_h = *(const short8*)AH[ks][lane];
            const short8 a_l = *(const short8*)AL[ks][lane];
            const size_t off = (size_t)(n * 16 + col) * PRE + ks * 32 + rowq * 8;
            const short8 b_h = *(const short8*)(p2h + off);
            const short8 b_l = *(const short8*)(p2l + off);
            acc = __builtin_amdgcn_mfma_f32_16x16x32_bf16(a_h, b_h, acc, 0, 0, 0);
            acc = __builtin_amdgcn_mfma_f32_16x16x32_bf16(a_l, b_h, acc, 0, 0, 0);
            acc = __builtin_amdgcn_mfma_f32_16x16x32_bf16(a_h, b_l, acc, 0, 0, 0);
        }
        const int j = wave * 16 + col;
        const float bb = b2[j];
        #pragma unroll
        for (int r = 0; r < 4; ++r)
            S[rowq * 4 + r][j] = fmaxf(acc[r] + bb, 0.f);
    }
    __syncthreads();
    // frag-convert h_pre (K=128)
    if (tid < 256) {
        const int sub = tid >> 6, ln = tid & 63;
        const int row = ln & 15, kk = sub * 32 + (ln >> 4) * 8;
        const float4 v0 = *(const float4*)&S[row][kk];
        const float4 v1 = *(const float4*)&S[row][kk + 4];
        const float av[8] = {v0.x, v0.y, v0.z, v0.w, v1.x, v1.y, v1.z, v1.w};
        short hi[8], lo[8];
        #pragma unroll
        for (int u = 0; u < 8; ++u) {
            const unsigned short h = f2bf(av[u]);
            hi[u] = (short)h; lo[u] = (short)f2bf(av[u] - bf2f(h));
        }
        *(short8*)AH[sub][ln] = *(const short8*)hi;
        *(short8*)AL[sub][ln] = *(const short8*)lo;
    }
    __syncthreads();

    // ---- gru gi = h_pre @ wi^T : N=768 (48 ntiles, 6/wave), K=128
    for (int t = 0; t < 6; ++t) {
        const int n = wave * 6 + t;
        f32x4 acc = {0.f, 0.f, 0.f, 0.f};
        #pragma unroll
        for (int ks = 0; ks < 4; ++ks) {
            const short8 a_h = *(const short8*)AH[ks][lane];
            const short8 a_l = *(const short8*)AL[ks][lane];
            const size_t off = (size_t)(n * 16 + col) * PRE + ks * 32 + rowq * 8;
            const short8 b_h = *(const short8*)(wih + off);
            const short8 b_l = *(const short8*)(wil + off);
            acc = __builtin_amdgcn_mfma_f32_16x16x32_bf16(a_h, b_h, acc, 0, 0, 0);
            acc = __builtin_amdgcn_mfma_f32_16x16x32_bf16(a_l, b_h, acc, 0, 0, 0);
            acc = __builtin_amdgcn_mfma_f32_16x16x32_bf16(a_h, b_l, acc, 0, 0, 0);
        }
        const int j = n * 16 + col;
        #pragma unroll
        for (int r = 0; r < 4; ++r) S[rowq * 4 + r][j] = acc[r];
    }
    __syncthreads();
    // frag-convert h_att (K=256, 8 subs, 512 slots)
    {
        const int sub = tid >> 6, ln = tid & 63;
        const int row = ln & 15, kk = sub * 32 + (ln >> 4) * 8;
        const float4 v0 = *(const float4*)&hs[row][kk];
        const float4 v1 = *(const float4*)&hs[row][kk + 4];
        const float av[8] = {v0.x, v0.y, v0.z, v0.w, v1.x, v1.y, v1.z, v1.w};
        short hi[8], lo[8];
        #pragma unroll
        for (int u = 0; u < 8; ++u) {
            const unsigned short h = f2bf(av[u]);
            hi[u] = (short)h; lo[u] = (short)f2bf(av[u] - bf2f(h));
        }
        *(short8*)AH[sub][ln] = *(const short8*)hi;
        *(short8*)AL[sub][ln] = *(const short8*)lo;
    }
    __syncthreads();

    // ---- gru gh = h_att @ wh^T : N=768, K=256 (8 subs)
    for (int t = 0; t < 6; ++t) {
        const int n = wave * 6 + t;
        f32x4 acc = {0.f, 0.f, 0.f, 0.f};
        #pragma unroll
        for (int ks = 0; ks < 8; ++ks) {
            const short8 a_h = *(const short8*)AH[ks][lane];
            const short8 a_l = *(const short8*)AL[ks][lane];
            const size_t off = (size_t)(n * 16 + col) * ATT + ks * 32 + rowq * 8;
            const short8 b_h = *(const short8*)(whh + off);
            const short8 b_l = *(const short8*)(whl + off);
            acc = __builtin_amdgcn_mfma_f32_16x16x32_bf16(a_h, b_h, acc, 0, 0, 0);
            acc = __builtin_amdgcn_mfma_f32_16x16x32_bf16(a_l, b_h, acc, 0, 0, 0);
            acc = __builtin_amdgcn_mfma_f32_16x16x32_bf16(a_h, b_l, acc, 0, 0, 0);
        }
        const int j = n * 16 + col;
        #pragma unroll
        for (int r = 0; r < 4; ++r) S2[rowq * 4 + r][j] = acc[r];
    }
    __syncthreads();

    // ---- gate math: h_att_new (16x256)
    for (int e = tid; e < 16 * ATT; e += 512) {
        const int b = e >> 8, j = e & 255;
        const float ir = S[b][j] + bi[j];
        const float iz = S[b][ATT + j] + bi[ATT + j];
        const float in_ = S[b][2 * ATT + j] + bi[2 * ATT + j];
        const float hr = S2[b][j] + bh[j];
        const float hz = S2[b][ATT + j] + bh[ATT + j];
        const float hn = S2[b][2 * ATT + j] + bh[2 * ATT + j];
        const float r = 1.f / (1.f + expf(-(ir + hr)));
        const float z = 1.f / (1.f + expf(-(iz + hz)));
        const float n = tanhf(in_ + r * hn);
        const float hnew = (1.f - z) * n + z * hs[b][j];
        h_att_out[(size_t)(mb + b) * ATT + j] = hnew;
        x_dec[(size_t)(mb + b) * RNN + j] = hnew;
        hs[b][j] = hnew;
    }
    __syncthreads();
    // frag-convert h_att_new (K=256)
    {
        const int sub = tid >> 6, ln = tid & 63;
        const int row = ln & 15, kk = sub * 32 + (ln >> 4) * 8;
        const float4 v0 = *(const float4*)&hs[row][kk];
        const float4 v1 = *(const float4*)&hs[row][kk + 4];
        const float av[8] = {v0.x, v0.y, v0.z, v0.w, v1.x, v1.y, v1.z, v1.w};
        short hi[8], lo[8];
        #pragma unroll
        for (int u = 0; u < 8; ++u) {
            const unsigned short h = f2bf(av[u]);
            hi[u] = (short)h; lo[u] = (short)f2bf(av[u] - bf2f(h));
        }
        *(short8*)AH[sub][ln] = *(const short8*)hi;
        *(short8*)AL[sub][ln] = *(const short8*)lo;
    }
    __syncthreads();

    // ---- q projection: N=512 (32 ntiles, 4/wave), K=256
    for (int t = 0; t < 4; ++t) {
        const int n = wave * 4 + t;
        f32x4 acc = {0.f, 0.f, 0.f, 0.f};
        #pragma unroll
        for (int ks = 0; ks < 8; ++ks) {
            const short8 a_h = *(const short8*)AH[ks][lane];
            const short8 a_l = *(const short8*)AL[ks][lane];
            const size_t off = (size_t)(n * 16 + col) * ATT + ks * 32 + rowq * 8;
            const short8 b_h = *(const short8*)(qwh + off);
            const short8 b_l = *(const short8*)(qwl + off);
            acc = __builtin_amdgcn_mfma_f32_16x16x32_bf16(a_h, b_h, acc, 0, 0, 0);
            acc = __builtin_amdgcn_mfma_f32_16x16x32_bf16(a_l, b_h, acc, 0, 0, 0);
            acc = __builtin_amdgcn_mfma_f32_16x16x32_bf16(a_h, b_l, acc, 0, 0, 0);
        }
        const int j = n * 16 + col;
        const float bb = qb[j];
        #pragma unroll
        for (int r = 0; r < 4; ++r)
            q[(size_t)(mb + rowq * 4 + r) * CTX + j] = acc[r] + bb;
    }
}

// ---------------------------------------------------------------------------
// Fused memory pass (single read of memory): e scores + ctx partials
// grid: dim3(8, B), 256 threads
// ---------------------------------------------------------------------------
__global__ void mempass_kernel(const float* __restrict__ mem, const float* __restrict__ w,
                               const float* __restrict__ q, float* __restrict__ e,
                               float* __restrict__ ctx_part) {
    const int b = blockIdx.y, slice = blockIdx.x;
    const int tid = threadIdx.x;
    const int wave = tid >> 6, lane = tid & 63;
    __shared__ float qs[CTX];
    __shared__ float ctx_s[4][CTX];
    for (int i = tid; i < CTX; i += 256) qs[i] = q[(size_t)b * CTX + i];
    __syncthreads();

    const int c0 = lane * 4;
    const int c1 = 256 + lane * 4;
    const float q0 = qs[c0], q1 = qs[c0 + 1], q2 = qs[c0 + 2], q3 = qs[c0 + 3];
    const float q4 = qs[c1], q5 = qs[c1 + 1], q6 = qs[c1 + 2], q7 = qs[c1 + 3];

    const float* mb = mem + (size_t)b * T * CTX;
    float acc[8] = {0.f, 0.f, 0.f, 0.f, 0.f, 0.f, 0.f, 0.f};
    const float invs = 0.04419417382415922f;  // 1/sqrt(512)
    const int t0 = slice * 64 + wave * 16;

    for (int i = 0; i < 16; ++i) {
        const int t = t0 + i;
        const float* row = mb + (size_t)t * CTX;
        const float4 m0 = *(const float4*)(row + c0);
        const float4 m1 = *(const float4*)(row + c1);
        const float wt = w[(size_t)b * T + t];
        float ep = m0.x * q0 + m0.y * q1 + m0.z * q2 + m0.w * q3
                 + m1.x * q4 + m1.y * q5 + m1.z * q6 + m1.w * q7;
        #pragma unroll
        for (int off = 32; off; off >>= 1) ep += __shfl_xor(ep, off);
        if (lane == 0) e[(size_t)b * T + t] = ep * invs;
        acc[0] += wt * m0.x; acc[1] += wt * m0.y; acc[2] += wt * m0.z; acc[3] += wt * m0.w;
        acc[4] += wt * m1.x; acc[5] += wt * m1.y; acc[6] += wt * m1.z; acc[7] += wt * m1.w;
    }
    ctx_s[wave][c0] = acc[0]; ctx_s[wave][c0 + 1] = acc[1]; ctx_s[wave][c0 + 2] = acc[2]; ctx_s[wave][c0 + 3] = acc[3];
    ctx_s[wave][c1] = acc[4]; ctx_s[wave][c1 + 1] = acc[5]; ctx_s[wave][c1 + 2] = acc[6]; ctx_s[wave][c1 + 3] = acc[7];
    __syncthreads();
    for (int c = tid; c < CTX; c += 256) {
        const float s = ctx_s[0][c] + ctx_s[1][c] + ctx_s[2][c] + ctx_s[3][c];
        ctx_part[((size_t)slice * B + b) * CTX + c] = s;
    }
}

// ---------------------------------------------------------------------------
// Fused mid: blocks 0..511 reduce ctx partials -> x_dec[:, 256:768]
//            blocks 512..767 softmax * Markov prior -> w_new
// ---------------------------------------------------------------------------
__global__ void mid_kernel(const float* __restrict__ part, float* __restrict__ x_dec,
                           const float* __restrict__ e, const float* __restrict__ w,
                           float* __restrict__ w_new) {
    const int tid = threadIdx.x;
    if (blockIdx.x < 512) {
        const int idx = blockIdx.x * 256 + tid;
        const int b = idx >> 9, c = idx & 511;
        float s = 0.f;
        #pragma unroll
        for (int sl = 0; sl < 8; ++sl) s += part[((size_t)sl * B + b) * CTX + c];
        x_dec[(size_t)b * RNN + ATT + c] = s;
        return;
    }
    const int b = blockIdx.x - 512;
    const int lane = tid & 63, wv = tid >> 6;
    __shared__ float red[4];
    const float* eb = e + (size_t)b * T;
    const float* wb = w + (size_t)b * T;
    const float e0 = eb[tid], e1 = eb[tid + 256];

    float m = fmaxf(e0, e1);
    #pragma unroll
    for (int o = 32; o; o >>= 1) m = fmaxf(m, __shfl_xor(m, o));
    if (lane == 0) red[wv] = m;
    __syncthreads();
    m = fmaxf(fmaxf(red[0], red[1]), fmaxf(red[2], red[3]));
    __syncthreads();

    const float x0 = expf(e0 - m), x1 = expf(e1 - m);
    float s = x0 + x1;
    #pragma unroll
    for (int o = 32; o; o >>= 1) s += __shfl_xor(s, o);
    if (lane == 0) red[wv] = s;
    __syncthreads();
    s = red[0] + red[1] + red[2] + red[3];
    __syncthreads();

    const float p0 = 0.5f * (wb[tid] + (tid > 0 ? wb[tid - 1] : 0.f));
    const float p1 = 0.5f * (wb[tid + 256] + wb[tid + 255]);
    const float m0 = (x0 / s) * p0;
    const float m1 = (x1 / s) * p1;
    float s2 = m0 + m1;
    #pragma unroll
    for (int o = 32; o; o >>= 1) s2 += __shfl_xor(s2, o);
    if (lane == 0) red[wv] = s2;
    __syncthreads();
    s2 = red[0] + red[1] + red[2] + red[3];
    const float inv = 1.f / (s2 + 1e-8f);
    w_new[(size_t)b * T + tid] = m0 * inv;
    w_new[(size_t)b * T + tid + 256] = m1 * inv;
}

// ---------------------------------------------------------------------------
// bf16-MFMA split-precision GEMM: C[256,2304] = A[256,768] @ W[2304,768]^T
// (unchanged from R4)
// ---------------------------------------------------------------------------
__global__ __launch_bounds__(256) void mfma_gemm_kernel(
        const float* __restrict__ Agi, const float* __restrict__ Agh,
        const float* __restrict__ Wgi, const float* __restrict__ Wgh,
        float* __restrict__ Cgi, float* __restrict__ Cgh) {
    const int mat = blockIdx.z;
    const float* __restrict__ A = mat ? Agh : Agi;
    const float* __restrict__ W = mat ? Wgh : Wgi;
    float* __restrict__ C = mat ? Cgh : Cgi;

    const int m0 = blockIdx.y * 64;
    const int n0 = blockIdx.x * 64;

    __shared__ __align__(16) short AH[4096];
    __shared__ __align__(16) short AL[4096];
    __shared__ __align__(16) short WH[4096];
    __shared__ __align__(16) short WL[4096];

    const int tid = threadIdx.x;
    const int lane = tid & 63;
    const int wave = tid >> 6;
    const int wm = wave >> 1, wn = wave & 1;

    f32x4 acc[2][2] = {{{0.f, 0.f, 0.f, 0.f}, {0.f, 0.f, 0.f, 0.f}},
                       {{0.f, 0.f, 0.f, 0.f}, {0.f, 0.f, 0.f, 0.f}}};

    for (int k0 = 0; k0 < RNN; k0 += 64) {
        #pragma unroll
        for (int si = 0; si < 2; ++si) {
            const int s = tid + si * 256;
            const int sub = s >> 6;
            const int ln = s & 63;
            const int row = (sub >> 1) * 16 + (ln & 15);
            const int kk = (sub & 1) * 32 + (ln >> 4) * 8;

            const float* ap = A + (size_t)(m0 + row) * RNN + k0 + kk;
            const float4 a0 = *(const float4*)ap;
            const float4 a1 = *(const float4*)(ap + 4);
            const float av[8] = {a0.x, a0.y, a0.z, a0.w, a1.x, a1.y, a1.z, a1.w};
            short hi[8], lo[8];
            #pragma unroll
            for (int u = 0; u < 8; ++u) {
                const unsigned short h = f2bf(av[u]);
                hi[u] = (short)h;
                lo[u] = (short)f2bf(av[u] - bf2f(h));
            }
            *(short8*)&AH[s * 8] = *(const short8*)hi;
            *(short8*)&AL[s * 8] = *(const short8*)lo;

            const float* wp = W + (size_t)(n0 + row) * RNN + k0 + kk;
            const float4 w0 = *(const float4*)wp;
            const float4 w1 = *(const float4*)(wp + 4);
            const float wv[8] = {w0.x, w0.y, w0.z, w0.w, w1.x, w1.y, w1.z, w1.w};
            #pragma unroll
            for (int u = 0; u < 8; ++u) {
                const unsigned short h = f2bf(wv[u]);
                hi[u] = (short)h;
                lo[u] = (short)f2bf(wv[u] - bf2f(h));
            }
            *(short8*)&WH[s * 8] = *(const short8*)hi;
            *(short8*)&WL[s * 8] = *(const short8*)lo;
        }
        __syncthreads();

        #pragma unroll
        for (int ks = 0; ks < 2; ++ks) {
            short8 ah[2], al[2], wh[2], wl[2];
            #pragma unroll
            for (int i = 0; i < 2; ++i) {
                const int asub = ((wm * 2 + i) * 2 + ks);
                ah[i] = *(const short8*)&AH[(asub * 64 + lane) * 8];
                al[i] = *(const short8*)&AL[(asub * 64 + lane) * 8];
                const int wsub = ((wn * 2 + i) * 2 + ks);
                wh[i] = *(const short8*)&WH[(wsub * 64 + lane) * 8];
                wl[i] = *(const short8*)&WL[(wsub * 64 + lane) * 8];
            }
            #pragma unroll
            for (int i = 0; i < 2; ++i)
                #pragma unroll
                for (int j = 0; j < 2; ++j) {
                    acc[i][j] = __builtin_amdgcn_mfma_f32_16x16x32_bf16(ah[i], wh[j], acc[i][j], 0, 0, 0);
                    acc[i][j] = __builtin_amdgcn_mfma_f32_16x16x32_bf16(al[i], wh[j], acc[i][j], 0, 0, 0);
                    acc[i][j] = __builtin_amdgcn_mfma_f32_16x16x32_bf16(ah[i], wl[j], acc[i][j], 0, 0, 0);
                }
        }
        __syncthreads();
    }

    const int rowq = lane >> 4, col = lane & 15;
    #pragma unroll
    for (int i = 0; i < 2; ++i)
        #pragma unroll
        for (int j = 0; j < 2; ++j) {
            const int rbase = m0 + wm * 32 + i * 16 + rowq * 4;
            const int cidx = n0 + wn * 32 + j * 16 + col;
            #pragma unroll
            for (int r = 0; r < 4; ++r)
                C[(size_t)(rbase + r) * G3 + cidx] = acc[i][j][r];
        }
}

// ---------------------------------------------------------------------------
// GRU epilogue: bias + gates + residual. grid: 768 blocks x 256 thr
// ---------------------------------------------------------------------------
__global__ void gru_res_kernel(const float* __restrict__ gi, const float* __restrict__ gh,
                               const float* __restrict__ x_in, const float* __restrict__ h_prev,
                               const float* __restrict__ bi, const float* __restrict__ bh,
                               float* __restrict__ out0, float* __restrict__ out1) {
    const int idx = blockIdx.x * 256 + threadIdx.x;
    const int b = idx / RNN, j = idx % RNN;
    const float* gib = gi + (size_t)b * G3;
    const float* ghb = gh + (size_t)b * G3;
    const float ir = gib[j] + bi[j];
    const float iz = gib[RNN + j] + bi[RNN + j];
    const float in_ = gib[2 * RNN + j] + bi[2 * RNN + j];
    const float hr = ghb[j] + bh[j];
    const float hz = ghb[RNN + j] + bh[RNN + j];
    const float hn = ghb[2 * RNN + j] + bh[2 * RNN + j];
    const float r = 1.f / (1.f + expf(-(ir + hr)));
    const float z = 1.f / (1.f + expf(-(iz + hz)));
    const float n = tanhf(in_ + r * hn);
    const float res = (1.f - z) * n + z * h_prev[idx] + x_in[idx];
    out0[idx] = res;
    if (out1) out1[idx] = res;
}

// ---------------------------------------------------------------------------
extern "C" void kernel_launch(void* const* d_in, const int* in_sizes, int n_in,
                              void* d_out, int out_size, void* d_ws, size_t ws_size,
                              hipStream_t stream) {
    const float* x       = (const float*)d_in[0];
    const float* w       = (const float*)d_in[1];
    const float* h_att   = (const float*)d_in[2];
    const float* h_dec0  = (const float*)d_in[3];
    const float* h_dec1  = (const float*)d_in[4];
    const float* memory  = (const float*)d_in[5];
    const float* pre_w1  = (const float*)d_in[6];
    const float* pre_b1  = (const float*)d_in[7];
    const float* pre_w2  = (const float*)d_in[8];
    const float* pre_b2  = (const float*)d_in[9];
    const float* att_wi  = (const float*)d_in[10];
    const float* att_wh  = (const float*)d_in[11];
    const float* att_bi  = (const float*)d_in[12];
    const float* att_bh  = (const float*)d_in[13];
    const float* q_w     = (const float*)d_in[14];
    const float* q_b     = (const float*)d_in[15];
    const float* dec0_wi = (const float*)d_in[16];
    const float* dec0_wh = (const float*)d_in[17];
    const float* dec0_bi = (const float*)d_in[18];
    const float* dec0_bh = (const float*)d_in[19];
    const float* dec1_wi = (const float*)d_in[20];
    const float* dec1_wh = (const float*)d_in[21];
    const float* dec1_bi = (const float*)d_in[22];
    const float* dec1_bh = (const float*)d_in[23];

    float* out = (float*)d_out;
    float* o_h1a = out;                    // h1        (256*768)
    float* o_wn  = out + 196608;           // w_new     (256*512)
    float* o_ha  = out + 327680;           // h_att_new (256*256)
    float* o_h0  = out + 393216;           // h0        (256*768)
    float* o_h1b = out + 589824;           // h1 again  (256*768)

    float* ws    = (float*)d_ws;
    float* q     = ws;                     // 131072
    float* e     = ws + 131072;            // 131072
    float* x_dec = ws + 262144;            // 196608
    float* ctxp  = ws + 458752;            // 1048576  (8 slices x B x 512)
    float* gi    = ws + 1507328;           // 589824
    float* gh    = ws + 2097152;           // 589824
    short* sb    = (short*)(ws + 2686976); // bf16 hi/lo area (16B aligned)
    short* p1h = sb;             short* p1l = sb + 20480;
    short* p2h = sb + 40960;     short* p2l = sb + 57344;
    short* wih = sb + 73728;     short* wil = sb + 172032;
    short* whh = sb + 270336;    short* whl = sb + 466944;
    short* qwh = sb + 663552;    short* qwl = sb + 794624;

    wconv_kernel<<<1808, 256, 0, stream>>>(pre_w1, pre_w2, att_wi, att_wh, q_w,
                                           p1h, p1l, p2h, p2l, wih, wil, whh, whl, qwh, qwl);
    front_mfma_kernel<<<16, 512, 0, stream>>>(x, pre_b1, pre_b2, h_att, att_bi, att_bh, q_b,
                                              p1h, p1l, p2h, p2l, wih, wil, whh, whl, qwh, qwl,
                                              o_ha, x_dec, q);
    mempass_kernel<<<dim3(8, B), 256, 0, stream>>>(memory, w, q, e, ctxp);
    mid_kernel<<<768, 256, 0, stream>>>(ctxp, x_dec, e, w, o_wn);

    mfma_gemm_kernel<<<dim3(G3 / 64, B / 64, 2), 256, 0, stream>>>(
        x_dec, h_dec0, dec0_wi, dec0_wh, gi, gh);
    gru_res_kernel<<<768, 256, 0, stream>>>(gi, gh, x_dec, h_dec0, dec0_bi, dec0_bh, o_h0, nullptr);

    mfma_gemm_kernel<<<dim3(G3 / 64, B / 64, 2), 256, 0, stream>>>(
        o_h0, h_dec1, dec1_wi, dec1_wh, gi, gh);
    gru_res_kernel<<<768, 256, 0, stream>>>(gi, gh, o_h0, h_dec1, dec1_bi, dec1_bh, o_h1a, o_h1b);
}